// Round 5
// baseline (298.651 us; speedup 1.0000x reference)
//
#include <hip/hip_runtime.h>
#include <hip/hip_bf16.h>
#include <stdint.h>

// MultiHeadAttention forward, MI355X/gfx950.
// Pipeline: cvt x->bf16 | cvt+transpose W->bf16 B^T | fused QKV GEMM (bf16 MFMA,
//           dbuf staging, Q pre-scaled by 1/sqrt(dk)*log2e) | transpose V per-head
//           (sigma-permuted columns) | flash attention (exp2-domain online softmax,
//           -m folded into MFMA C-init, DPP max-reduce, ones-MFMA row sums,
//           cvt_pk packed P stores, double-buffered K/V, XOR-swizzled LDS) |
//           out GEMM (dbuf).
// Workspace layout (needs 56 MiB):
//   xb 0..8M | Wt(QKVO) 8..16M | Qb 16..24M | Kb 24..32M | Vb 32..40M
//   | Vt 40..48M | ctx 48..56M

#define DM 1024
#define SEQ 4096
#define NH 16
#define DK 64

// 1/sqrt(64) * log2(e): scores come out of QK^T already in exp2 domain.
#define QSCALE 0.18033688011112042f

typedef __attribute__((ext_vector_type(8))) short bf16x8;
typedef __attribute__((ext_vector_type(4))) float f32x4;
typedef __attribute__((ext_vector_type(2))) uint32_t u32x2;

__device__ __forceinline__ short f2bf(float f) {
  union { float f; uint32_t u; } x; x.f = f;
  uint32_t r = x.u + 0x7fffu + ((x.u >> 16) & 1u);
  return (short)(r >> 16);
}

__device__ __forceinline__ void gl_lds16(const void* g, void* l) {
  __builtin_amdgcn_global_load_lds(
      (const __attribute__((address_space(1))) void*)g,
      (__attribute__((address_space(3))) void*)l, 16, 0, 0);
}

// max with a DPP-permuted copy of x (16-lane-group reduction building block)
template <int CTRL>
__device__ __forceinline__ float dppmax(float x) {
  union { float f; int i; } u; u.f = x;
  int p = __builtin_amdgcn_update_dpp(u.i, u.i, CTRL, 0xf, 0xf, false);
  union { int i; float f; } v; v.i = p;
  return fmaxf(x, v.f);
}

// ---------- fp32 -> bf16 (x) ----------
__global__ __launch_bounds__(256) void cvt_x_k(const float* __restrict__ in,
                                               short* __restrict__ out) {
  size_t i = (size_t)blockIdx.x * 256 + threadIdx.x;
  const float4* ip = (const float4*)in;
  float4 a = ip[2 * i], b = ip[2 * i + 1];
  bf16x8 o;
  o[0] = f2bf(a.x); o[1] = f2bf(a.y); o[2] = f2bf(a.z); o[3] = f2bf(a.w);
  o[4] = f2bf(b.x); o[5] = f2bf(b.y); o[6] = f2bf(b.z); o[7] = f2bf(b.w);
  *(bf16x8*)(out + 8 * i) = o;
}

// ---------- W [k][n] fp32 -> Wt [n][k] bf16 (tiled transpose), z = which W ----------
__global__ __launch_bounds__(256) void cvt_wt_k(const float* __restrict__ W0,
                                                const float* __restrict__ W1,
                                                const float* __restrict__ W2,
                                                const float* __restrict__ W3,
                                                short* __restrict__ Wt0) {
  __shared__ alignas(16) short T[64][66];
  const int z = blockIdx.z;
  const float* W = (z == 0) ? W0 : (z == 1) ? W1 : (z == 2) ? W2 : W3;
  short* Wt = Wt0 + (size_t)z * (DM * DM);
  const int k0 = blockIdx.y * 64, n0 = blockIdx.x * 64;
#pragma unroll
  for (int rep = 0; rep < 16; ++rep) {
    int lin = rep * 256 + threadIdx.x;
    int i = lin >> 6, j = lin & 63;
    T[i][j] = f2bf(W[(size_t)(k0 + i) * DM + n0 + j]);
  }
  __syncthreads();
#pragma unroll
  for (int rep = 0; rep < 16; ++rep) {
    int lin = rep * 256 + threadIdx.x;
    int n = lin >> 6, kk = lin & 63;
    Wt[(size_t)(n0 + n) * DM + k0 + kk] = T[kk][n];
  }
}

// ---------- V [s][h*64+d] bf16 -> Vt [h*64+d][s] bf16, sigma-permuted columns ----
// sigma(c) = 4*(c&15) + (c>>4) within each 64-col block; matches P-store layout.
__global__ __launch_bounds__(256) void trans_v_k(const short* __restrict__ V,
                                                 short* __restrict__ Vt) {
  __shared__ alignas(16) short T[64][66];
  const int s0 = blockIdx.x * 64, h = blockIdx.y;
#pragma unroll
  for (int rep = 0; rep < 16; ++rep) {
    int lin = rep * 256 + threadIdx.x;
    int i = lin >> 6, j = lin & 63;
    T[i][j] = V[(size_t)(s0 + i) * DM + h * DK + j];
  }
  __syncthreads();
#pragma unroll
  for (int rep = 0; rep < 16; ++rep) {
    int lin = rep * 256 + threadIdx.x;
    int d = lin >> 6, ss = lin & 63;
    int sp = ((ss & 15) << 2) + (ss >> 4);   // sigma(ss)
    Vt[((size_t)h * DK + d) * SEQ + s0 + sp] = T[ss][d];
  }
}

// ---------- fused QKV GEMM: out[z] = xb @ Wt[z]^T + b[z], bf16 out, dbuf ----------
__global__ __launch_bounds__(256) void gemm_qkv(
    const short* __restrict__ xb, const short* __restrict__ Wt0,
    const float* __restrict__ bq, const float* __restrict__ bk,
    const float* __restrict__ bv, short* __restrict__ out0) {
  const int z = blockIdx.z;
  const short* Bt = Wt0 + (size_t)z * (DM * DM);
  const float* bias = (z == 0) ? bq : (z == 1) ? bk : bv;
  const float qs = (z == 0) ? QSCALE : 1.0f;
  short* out = out0 + (size_t)z * ((size_t)SEQ * DM);

  __shared__ alignas(16) short As[2][128 * 32];
  __shared__ alignas(16) short Bs[2][128 * 32];
  const int tid = threadIdx.x, lane = tid & 63, w = tid >> 6;
  const int bm = blockIdx.y * 128, bn = blockIdx.x * 128;
  const int wm = (w >> 1) * 64, wn = (w & 1) * 64;
  f32x4 acc[4][4] = {};

  auto stage = [&](int buf, int kt) {
#pragma unroll
    for (int c = 0; c < 2; ++c) {
      int i = w * 2 + c;
      int ob = i * 1024 + lane * 16;
      int row = ob >> 6, colb = ob & 63;
      gl_lds16((const char*)xb + ((size_t)(bm + row) * DM + kt) * 2 + colb,
               (char*)&As[buf][0] + i * 1024);
      gl_lds16((const char*)Bt + ((size_t)(bn + row) * DM + kt) * 2 + colb,
               (char*)&Bs[buf][0] + i * 1024);
    }
  };

  stage(0, 0);
  for (int t = 0; t < DM / 32; ++t) {
    const int cur = t & 1;
    __syncthreads();
    if (t < DM / 32 - 1) stage(cur ^ 1, (t + 1) * 32);
    bf16x8 bfr[4];
#pragma unroll
    for (int n = 0; n < 4; ++n)
      bfr[n] = *(const bf16x8*)((const char*)&Bs[cur][0] +
                                (wn + n * 16 + (lane & 15)) * 64 + (lane >> 4) * 16);
    __builtin_amdgcn_s_setprio(1);
#pragma unroll
    for (int m = 0; m < 4; ++m) {
      bf16x8 af = *(const bf16x8*)((const char*)&As[cur][0] +
                                   (wm + m * 16 + (lane & 15)) * 64 + (lane >> 4) * 16);
#pragma unroll
      for (int n = 0; n < 4; ++n)
        acc[m][n] = __builtin_amdgcn_mfma_f32_16x16x32_bf16(af, bfr[n], acc[m][n], 0, 0, 0);
    }
    __builtin_amdgcn_s_setprio(0);
  }
  const int r0 = bm + wm + ((lane >> 4) << 2);
  const int c0 = bn + wn + (lane & 15);
#pragma unroll
  for (int n = 0; n < 4; ++n) {
    const int col = c0 + n * 16;
    const float b = bias[col];
#pragma unroll
    for (int m = 0; m < 4; ++m)
#pragma unroll
      for (int r = 0; r < 4; ++r)
        out[(size_t)(r0 + m * 16 + r) * DM + col] = f2bf((acc[m][n][r] + b) * qs);
  }
}

// ---------- output GEMM: out = ctx @ WtO^T + b_o, fp32 out, dbuf ----------
__global__ __launch_bounds__(256) void gemm_out(
    const short* __restrict__ A, const short* __restrict__ Bt,
    const float* __restrict__ bias, float* __restrict__ out) {
  __shared__ alignas(16) short As[2][128 * 32];
  __shared__ alignas(16) short Bs[2][128 * 32];
  const int tid = threadIdx.x, lane = tid & 63, w = tid >> 6;
  const int bm = blockIdx.y * 128, bn = blockIdx.x * 128;
  const int wm = (w >> 1) * 64, wn = (w & 1) * 64;
  f32x4 acc[4][4] = {};

  auto stage = [&](int buf, int kt) {
#pragma unroll
    for (int c = 0; c < 2; ++c) {
      int i = w * 2 + c;
      int ob = i * 1024 + lane * 16;
      int row = ob >> 6, colb = ob & 63;
      gl_lds16((const char*)A + ((size_t)(bm + row) * DM + kt) * 2 + colb,
               (char*)&As[buf][0] + i * 1024);
      gl_lds16((const char*)Bt + ((size_t)(bn + row) * DM + kt) * 2 + colb,
               (char*)&Bs[buf][0] + i * 1024);
    }
  };

  stage(0, 0);
  for (int t = 0; t < DM / 32; ++t) {
    const int cur = t & 1;
    __syncthreads();
    if (t < DM / 32 - 1) stage(cur ^ 1, (t + 1) * 32);
    bf16x8 bfr[4];
#pragma unroll
    for (int n = 0; n < 4; ++n)
      bfr[n] = *(const bf16x8*)((const char*)&Bs[cur][0] +
                                (wn + n * 16 + (lane & 15)) * 64 + (lane >> 4) * 16);
    __builtin_amdgcn_s_setprio(1);
#pragma unroll
    for (int m = 0; m < 4; ++m) {
      bf16x8 af = *(const bf16x8*)((const char*)&As[cur][0] +
                                   (wm + m * 16 + (lane & 15)) * 64 + (lane >> 4) * 16);
#pragma unroll
      for (int n = 0; n < 4; ++n)
        acc[m][n] = __builtin_amdgcn_mfma_f32_16x16x32_bf16(af, bfr[n], acc[m][n], 0, 0, 0);
    }
    __builtin_amdgcn_s_setprio(0);
  }
  const int r0 = bm + wm + ((lane >> 4) << 2);
  const int c0 = bn + wn + (lane & 15);
#pragma unroll
  for (int n = 0; n < 4; ++n) {
    const int col = c0 + n * 16;
    const float b = bias[col];
#pragma unroll
    for (int m = 0; m < 4; ++m)
#pragma unroll
      for (int r = 0; r < 4; ++r)
        out[(size_t)(r0 + m * 16 + r) * DM + col] = acc[m][n][r] + b;
  }
}

// ---------- flash attention ----------
// Scores arrive in exp2 domain with the running max ALREADY subtracted:
// QK^T MFMA chains start from C = mvec = {-m} (D and C may differ), so the
// common path is P = exp2(sc) with no per-element subtract.  The 16-lane max
// reduce is pure-VALU DPP (quad_perm xor1/xor2, row_half_mirror, row_mirror).
// Per 4-row lane-group shared max (exact: per-row P scale consistent since
// each row is written by exactly one group).  Row sums by ones-MFMA.  P packed
// via v_cvt_pk_bf16_f32 into sigma-permuted columns matching trans_v_k.
// Defer-max: rescale only when a group's tile max exceeds the running max by 8.
__global__ __launch_bounds__(256) void attn_k(
    const short* __restrict__ Qb, const short* __restrict__ Kb,
    const short* __restrict__ Vt, short* __restrict__ ctx) {
  const int h = blockIdx.y, qt = blockIdx.x;
  const int tid = threadIdx.x, lane = tid & 63, w = tid >> 6;
  __shared__ alignas(16) short Ks[2][64 * 64];   // [s][d] swizzled
  __shared__ alignas(16) short Vs[2][64 * 64];   // [d][s'] swizzled, sigma cols
  __shared__ alignas(16) short Pl[4][16 * 64];   // per-wave P [16 q][64 s'] swizzled

  const int qr = qt * 64 + w * 16 + (lane & 15);
  const short* qp = Qb + (size_t)qr * DM + h * DK + ((lane >> 4) * 8);
  const bf16x8 qf0 = *(const bf16x8*)qp;
  const bf16x8 qf1 = *(const bf16x8*)(qp + 32);

  bf16x8 ones;
#pragma unroll
  for (int j = 0; j < 8; ++j) ones[j] = (short)0x3F80;

  f32x4 o[4] = {};
  f32x4 ol = {};                    // row sums (replicated across row's lanes)
  f32x4 mvec = {3000.f, 3000.f, 3000.f, 3000.f};  // = -m, m init -3000

  const int xk = (lane & 7) << 4;   // read-side XOR
  char* pbase = (char*)&Pl[w][0];
  const int g = lane >> 4, cl = lane & 15;

  auto stage = [&](int buf, int s0) {
#pragma unroll
    for (int c = 0; c < 2; ++c) {
      int i = w * 2 + c;
      int ob = i * 1024 + lane * 16;
      int row = ob >> 7, colb = ob & 127;
      int src = colb ^ ((row & 7) << 4);   // inverse-swizzle the SOURCE
      gl_lds16((const char*)Kb + ((size_t)(s0 + row) * DM + h * DK) * 2 + src,
               (char*)&Ks[buf][0] + i * 1024);
      gl_lds16((const char*)Vt + ((size_t)(h * DK + row) * SEQ + s0) * 2 + src,
               (char*)&Vs[buf][0] + i * 1024);
    }
  };

  stage(0, 0);

  for (int t = 0; t < SEQ / 64; ++t) {
    const int cur = t & 1;
    __syncthreads();                 // stage(t) landed; buf[cur^1] reads done
    if (t < SEQ / 64 - 1) stage(cur ^ 1, (t + 1) * 64);

    const char* kbase = (const char*)&Ks[cur][0];
    const char* vbase = (const char*)&Vs[cur][0];

    // sc = Qs K^T - m   (C-init with mvec; D may differ from C)
    f32x4 sc[4];
    __builtin_amdgcn_s_setprio(1);
#pragma unroll
    for (int n = 0; n < 4; ++n) {
      bf16x8 b0 = *(const bf16x8*)(kbase + (n * 16 + cl) * 128 + ((g * 16) ^ xk));
      sc[n] = __builtin_amdgcn_mfma_f32_16x16x32_bf16(qf0, b0, mvec, 0, 0, 0);
      bf16x8 b1 = *(const bf16x8*)(kbase + (n * 16 + cl) * 128 + ((64 + g * 16) ^ xk));
      sc[n] = __builtin_amdgcn_mfma_f32_16x16x32_bf16(qf1, b1, sc[n], 0, 0, 0);
    }
    __builtin_amdgcn_s_setprio(0);

    // group max of (S - m) over 4 rows x 64 cols, DPP reduce within 16 lanes
    float lm = fmaxf(fmaxf(fmaxf(sc[0][0], sc[0][1]), fmaxf(sc[0][2], sc[0][3])),
                     fmaxf(fmaxf(sc[1][0], sc[1][1]), fmaxf(sc[1][2], sc[1][3])));
    lm = fmaxf(lm, fmaxf(fmaxf(fmaxf(sc[2][0], sc[2][1]), fmaxf(sc[2][2], sc[2][3])),
                         fmaxf(fmaxf(sc[3][0], sc[3][1]), fmaxf(sc[3][2], sc[3][3]))));
    lm = dppmax<0xB1>(lm);   // quad_perm [1,0,3,2]  (xor 1)
    lm = dppmax<0x4E>(lm);   // quad_perm [2,3,0,1]  (xor 2)
    lm = dppmax<0x141>(lm);  // row_half_mirror      (covers xor 4)
    lm = dppmax<0x140>(lm);  // row_mirror           (covers xor 8)
    if (!__all(lm <= 8.f)) {
      float dm = fmaxf(lm, 0.f);     // group-uniform growth of m
      float al = exp2f(-dm);
#pragma unroll
      for (int n = 0; n < 4; ++n) {
        o[n][0] *= al; o[n][1] *= al; o[n][2] *= al; o[n][3] *= al;
        sc[n][0] -= dm; sc[n][1] -= dm; sc[n][2] -= dm; sc[n][3] -= dm;
      }
      ol[0] *= al; ol[1] *= al; ol[2] *= al; ol[3] *= al;
      mvec[0] -= dm; mvec[1] -= dm; mvec[2] -= dm; mvec[3] -= dm;
    }

    // P = exp2(sc), pack pairs, one b64 store per row
#pragma unroll
    for (int r = 0; r < 4; ++r) {
      const int prow = g * 4 + r;
      float p0 = exp2f(sc[0][r]), p1 = exp2f(sc[1][r]);
      float p2 = exp2f(sc[2][r]), p3 = exp2f(sc[3][r]);
      uint32_t u0, u1;
      asm("v_cvt_pk_bf16_f32 %0, %1, %2" : "=v"(u0) : "v"(p0), "v"(p1));
      asm("v_cvt_pk_bf16_f32 %0, %1, %2" : "=v"(u1) : "v"(p2), "v"(p3));
      u32x2 uu; uu[0] = u0; uu[1] = u1;
      *(u32x2*)(pbase + prow * 128 + ((cl * 8) ^ ((prow & 7) << 4))) = uu;
    }

    // O += P V ; l += P 1
    __builtin_amdgcn_s_setprio(1);
#pragma unroll
    for (int kk = 0; kk < 2; ++kk) {
      bf16x8 pa = *(const bf16x8*)(pbase + cl * 128 + ((kk * 64 + g * 16) ^ xk));
      ol = __builtin_amdgcn_mfma_f32_16x16x32_bf16(pa, ones, ol, 0, 0, 0);
#pragma unroll
      for (int n = 0; n < 4; ++n) {
        bf16x8 vb = *(const bf16x8*)(vbase + (n * 16 + cl) * 128 +
                                     ((kk * 64 + g * 16) ^ xk));
        o[n] = __builtin_amdgcn_mfma_f32_16x16x32_bf16(pa, vb, o[n], 0, 0, 0);
      }
    }
    __builtin_amdgcn_s_setprio(0);
  }

#pragma unroll
  for (int r = 0; r < 4; ++r) {
    float inv = 1.f / ol[r];
    int row = qt * 64 + w * 16 + g * 4 + r;
#pragma unroll
    for (int n = 0; n < 4; ++n)
      ctx[(size_t)row * DM + h * DK + n * 16 + cl] = f2bf(o[n][r] * inv);
  }
}

extern "C" void kernel_launch(void* const* d_in, const int* in_sizes, int n_in,
                              void* d_out, int out_size, void* d_ws, size_t ws_size,
                              hipStream_t stream) {
  const float* x  = (const float*)d_in[0];
  const float* Wq = (const float*)d_in[1];
  const float* bq = (const float*)d_in[2];
  const float* Wk = (const float*)d_in[3];
  const float* bk = (const float*)d_in[4];
  const float* Wv = (const float*)d_in[5];
  const float* bv = (const float*)d_in[6];
  const float* Wo = (const float*)d_in[7];
  const float* bo = (const float*)d_in[8];

  char* ws = (char*)d_ws;
  short* xb  = (short*)(ws + (size_t)0);
  short* Wt  = (short*)(ws + ((size_t)8 << 20));
  short* Qb  = (short*)(ws + ((size_t)16 << 20));
  short* Kb  = (short*)(ws + ((size_t)24 << 20));
  short* Vb  = (short*)(ws + ((size_t)32 << 20));
  short* Vt  = (short*)(ws + ((size_t)40 << 20));
  short* ctx = (short*)(ws + ((size_t)48 << 20));

  cvt_x_k<<<2048, 256, 0, stream>>>(x, xb);
  cvt_wt_k<<<dim3(16, 16, 4), 256, 0, stream>>>(Wq, Wk, Wv, Wo, Wt);
  gemm_qkv<<<dim3(DM / 128, SEQ / 128, 3), 256, 0, stream>>>(xb, Wt, bq, bk, bv, Qb);
  trans_v_k<<<dim3(SEQ / 64, NH), 256, 0, stream>>>(Vb, Vt);
  attn_k<<<dim3(SEQ / 64, NH), 256, 0, stream>>>(Qb, Kb, Vt, ctx);
  gemm_out<<<dim3(DM / 128, SEQ / 128), 256, 0, stream>>>(
      ctx, Wt + (size_t)3 * (DM * DM), bo, (float*)d_out);
}

// Round 10
// 294.014 us; speedup vs baseline: 1.0158x; 1.0158x over previous
//
#include <hip/hip_runtime.h>
#include <hip/hip_bf16.h>
#include <stdint.h>

// MultiHeadAttention forward, MI355X/gfx950.
// Pipeline: cvt x->bf16 | cvt+transpose W->bf16 B^T | fused QKV GEMM (bf16 MFMA,
//           Q pre-scaled by 1/sqrt(dk)*log2e) | transpose V per-head |
//           flash attention (32x32 MFMA, swapped S^T=K.Q^T so softmax is in-lane,
//           P register-resident; cross-half exchange via ds_bpermute/shfl_xor
//           [semantics-certain], -m folded into MFMA C-init, dbuf K/V,
//           XOR-swizzled LDS) | out GEMM.
// Workspace layout (needs 56 MiB):
//   xb 0..8M | Wt(QKVO) 8..16M | Qb 16..24M | Kb 24..32M | Vb 32..40M
//   | Vt 40..48M | ctx 48..56M

#define DM 1024
#define SEQ 4096
#define NH 16
#define DK 64

// 1/sqrt(64) * log2(e): scores come out of QK^T already in exp2 domain.
#define QSCALE 0.18033688011112042f

typedef __attribute__((ext_vector_type(8))) short bf16x8;
typedef __attribute__((ext_vector_type(4))) float f32x4;
typedef __attribute__((ext_vector_type(16))) float f32x16;
typedef __attribute__((ext_vector_type(2))) uint32_t u32x2;
typedef __attribute__((ext_vector_type(4))) uint32_t u32x4;

__device__ __forceinline__ short f2bf(float f) {
  union { float f; uint32_t u; } x; x.f = f;
  uint32_t r = x.u + 0x7fffu + ((x.u >> 16) & 1u);
  return (short)(r >> 16);
}

__device__ __forceinline__ void gl_lds16(const void* g, void* l) {
  __builtin_amdgcn_global_load_lds(
      (const __attribute__((address_space(1))) void*)g,
      (__attribute__((address_space(3))) void*)l, 16, 0, 0);
}

__device__ __forceinline__ uint32_t cvtpk(float lo, float hi) {
  uint32_t r;
  asm("v_cvt_pk_bf16_f32 %0, %1, %2" : "=v"(r) : "v"(lo), "v"(hi));
  return r;
}

// value from lane (own ^ 32) — ds_bpermute, semantics certain.
__device__ __forceinline__ uint32_t xlane(uint32_t v, int lane) {
  return (uint32_t)__builtin_amdgcn_ds_bpermute(((lane ^ 32) << 2), (int)v);
}

// ---------- fp32 -> bf16 (x) ----------
__global__ __launch_bounds__(256) void cvt_x_k(const float* __restrict__ in,
                                               short* __restrict__ out) {
  size_t i = (size_t)blockIdx.x * 256 + threadIdx.x;
  const float4* ip = (const float4*)in;
  float4 a = ip[2 * i], b = ip[2 * i + 1];
  bf16x8 o;
  o[0] = f2bf(a.x); o[1] = f2bf(a.y); o[2] = f2bf(a.z); o[3] = f2bf(a.w);
  o[4] = f2bf(b.x); o[5] = f2bf(b.y); o[6] = f2bf(b.z); o[7] = f2bf(b.w);
  *(bf16x8*)(out + 8 * i) = o;
}

// ---------- W [k][n] fp32 -> Wt [n][k] bf16 (tiled transpose), z = which W ----------
__global__ __launch_bounds__(256) void cvt_wt_k(const float* __restrict__ W0,
                                                const float* __restrict__ W1,
                                                const float* __restrict__ W2,
                                                const float* __restrict__ W3,
                                                short* __restrict__ Wt0) {
  __shared__ alignas(16) short T[64][66];
  const int z = blockIdx.z;
  const float* W = (z == 0) ? W0 : (z == 1) ? W1 : (z == 2) ? W2 : W3;
  short* Wt = Wt0 + (size_t)z * (DM * DM);
  const int k0 = blockIdx.y * 64, n0 = blockIdx.x * 64;
#pragma unroll
  for (int rep = 0; rep < 16; ++rep) {
    int lin = rep * 256 + threadIdx.x;
    int i = lin >> 6, j = lin & 63;
    T[i][j] = f2bf(W[(size_t)(k0 + i) * DM + n0 + j]);
  }
  __syncthreads();
#pragma unroll
  for (int rep = 0; rep < 16; ++rep) {
    int lin = rep * 256 + threadIdx.x;
    int n = lin >> 6, kk = lin & 63;
    Wt[(size_t)(n0 + n) * DM + k0 + kk] = T[kk][n];
  }
}

// ---------- V [s][h*64+d] bf16 -> Vt [h*64+d][s] bf16 (plain transpose) ----------
__global__ __launch_bounds__(256) void trans_v_k(const short* __restrict__ V,
                                                 short* __restrict__ Vt) {
  __shared__ alignas(16) short T[64][66];
  const int s0 = blockIdx.x * 64, h = blockIdx.y;
#pragma unroll
  for (int rep = 0; rep < 16; ++rep) {
    int lin = rep * 256 + threadIdx.x;
    int i = lin >> 6, j = lin & 63;
    T[i][j] = V[(size_t)(s0 + i) * DM + h * DK + j];
  }
  __syncthreads();
#pragma unroll
  for (int rep = 0; rep < 16; ++rep) {
    int lin = rep * 256 + threadIdx.x;
    int d = lin >> 6, ss = lin & 63;
    Vt[((size_t)h * DK + d) * SEQ + s0 + ss] = T[ss][d];
  }
}

// ---------- fused QKV GEMM: out[z] = xb @ Wt[z]^T + b[z], bf16 out ----------
// (r3-measured-best form: single-buffered, 2 barriers per K-step)
__global__ __launch_bounds__(256) void gemm_qkv(
    const short* __restrict__ xb, const short* __restrict__ Wt0,
    const float* __restrict__ bq, const float* __restrict__ bk,
    const float* __restrict__ bv, short* __restrict__ out0) {
  const int z = blockIdx.z;
  const short* Bt = Wt0 + (size_t)z * (DM * DM);
  const float* bias = (z == 0) ? bq : (z == 1) ? bk : bv;
  const float qs = (z == 0) ? QSCALE : 1.0f;
  short* out = out0 + (size_t)z * ((size_t)SEQ * DM);

  __shared__ alignas(16) short As[128 * 32];
  __shared__ alignas(16) short Bs[128 * 32];
  const int tid = threadIdx.x, lane = tid & 63, w = tid >> 6;
  const int bm = blockIdx.y * 128, bn = blockIdx.x * 128;
  const int wm = (w >> 1) * 64, wn = (w & 1) * 64;
  f32x4 acc[4][4] = {};

  for (int kt = 0; kt < DM; kt += 32) {
    __syncthreads();
#pragma unroll
    for (int c = 0; c < 2; ++c) {
      int i = w * 2 + c;
      int ob = i * 1024 + lane * 16;
      int row = ob >> 6, colb = ob & 63;
      gl_lds16((const char*)xb + ((size_t)(bm + row) * DM + kt) * 2 + colb,
               (char*)As + i * 1024);
      gl_lds16((const char*)Bt + ((size_t)(bn + row) * DM + kt) * 2 + colb,
               (char*)Bs + i * 1024);
    }
    __syncthreads();
    bf16x8 bfr[4];
#pragma unroll
    for (int n = 0; n < 4; ++n)
      bfr[n] = *(const bf16x8*)((const char*)Bs +
                                (wn + n * 16 + (lane & 15)) * 64 + (lane >> 4) * 16);
#pragma unroll
    for (int m = 0; m < 4; ++m) {
      bf16x8 af = *(const bf16x8*)((const char*)As +
                                   (wm + m * 16 + (lane & 15)) * 64 + (lane >> 4) * 16);
#pragma unroll
      for (int n = 0; n < 4; ++n)
        acc[m][n] = __builtin_amdgcn_mfma_f32_16x16x32_bf16(af, bfr[n], acc[m][n], 0, 0, 0);
    }
  }
  const int r0 = bm + wm + ((lane >> 4) << 2);
  const int c0 = bn + wn + (lane & 15);
#pragma unroll
  for (int n = 0; n < 4; ++n) {
    const int col = c0 + n * 16;
    const float b = bias[col];
#pragma unroll
    for (int m = 0; m < 4; ++m)
#pragma unroll
      for (int r = 0; r < 4; ++r)
        out[(size_t)(r0 + m * 16 + r) * DM + col] = f2bf((acc[m][n][r] + b) * qs);
  }
}

// ---------- output GEMM: out = ctx @ WtO^T + b_o, fp32 out ----------
__global__ __launch_bounds__(256) void gemm_out(
    const short* __restrict__ A, const short* __restrict__ Bt,
    const float* __restrict__ bias, float* __restrict__ out) {
  __shared__ alignas(16) short As[128 * 32];
  __shared__ alignas(16) short Bs[128 * 32];
  const int tid = threadIdx.x, lane = tid & 63, w = tid >> 6;
  const int bm = blockIdx.y * 128, bn = blockIdx.x * 128;
  const int wm = (w >> 1) * 64, wn = (w & 1) * 64;
  f32x4 acc[4][4] = {};

  for (int kt = 0; kt < DM; kt += 32) {
    __syncthreads();
#pragma unroll
    for (int c = 0; c < 2; ++c) {
      int i = w * 2 + c;
      int ob = i * 1024 + lane * 16;
      int row = ob >> 6, colb = ob & 63;
      gl_lds16((const char*)A + ((size_t)(bm + row) * DM + kt) * 2 + colb,
               (char*)As + i * 1024);
      gl_lds16((const char*)Bt + ((size_t)(bn + row) * DM + kt) * 2 + colb,
               (char*)Bs + i * 1024);
    }
    __syncthreads();
    bf16x8 bfr[4];
#pragma unroll
    for (int n = 0; n < 4; ++n)
      bfr[n] = *(const bf16x8*)((const char*)Bs +
                                (wn + n * 16 + (lane & 15)) * 64 + (lane >> 4) * 16);
#pragma unroll
    for (int m = 0; m < 4; ++m) {
      bf16x8 af = *(const bf16x8*)((const char*)As +
                                   (wm + m * 16 + (lane & 15)) * 64 + (lane >> 4) * 16);
#pragma unroll
      for (int n = 0; n < 4; ++n)
        acc[m][n] = __builtin_amdgcn_mfma_f32_16x16x32_bf16(af, bfr[n], acc[m][n], 0, 0, 0);
    }
  }
  const int r0 = bm + wm + ((lane >> 4) << 2);
  const int c0 = bn + wn + (lane & 15);
#pragma unroll
  for (int n = 0; n < 4; ++n) {
    const int col = c0 + n * 16;
    const float b = bias[col];
#pragma unroll
    for (int m = 0; m < 4; ++m)
#pragma unroll
      for (int r = 0; r < 4; ++r)
        out[(size_t)(r0 + m * 16 + r) * DM + col] = acc[m][n][r] + b;
  }
}

// ---------- flash attention, 32x32 MFMA, swapped operands ----------
// Per block: 2 waves, each owns 32 q-rows (QBLK=64); KV tile 64, dbuf LDS.
// S^T = K.Q^T: A=K (LDS, XOR-swizzled), B=Q^T (registers), C-init = {-m}.
// C-layout (m74/m101-verified): lane holds col q=lane&31,
// kv=(reg&3)+8*(reg>>2)+4*(lane>>5)+32*blk -> softmax over kv is an in-lane
// tree + one __shfl_xor(·,32). P stays in registers: cvt_pk pairs (quad q' of
// half hh holds kv base 8q'+4hh), then per kstep the two cross-half quads are
// fetched with ds_bpermute(lane^32) and hh-selects (semantics-certain).
// PV: O^T = Vt.P (A=Vt LDS, B=P registers).
__global__ __launch_bounds__(128, 2) void attn_k(
    const short* __restrict__ Qb, const short* __restrict__ Kb,
    const short* __restrict__ Vt, short* __restrict__ ctx) {
  const int h = blockIdx.y, qt = blockIdx.x;
  const int tid = threadIdx.x, lane = tid & 63, w = tid >> 6;
  __shared__ alignas(16) short Ks[2][64 * 64];   // [kv][dk], swizzled
  __shared__ alignas(16) short Vs[2][64 * 64];   // [d][kv], swizzled

  const int cq = lane & 31, hh = lane >> 5;
  const int qrow = qt * 64 + w * 32 + cq;

  bf16x8 qf[4];
  {
    const short* qp = Qb + (size_t)qrow * DM + h * DK + hh * 8;
#pragma unroll
    for (int ks = 0; ks < 4; ++ks) qf[ks] = *(const bf16x8*)(qp + ks * 16);
  }

  f32x16 o0 = {}, o1 = {};          // O^T accum, d-blocks 0/1
  float ol = 0.f;                   // own-half softmax denom
  f32x16 mv;                        // broadcast of -m (C-init for QK^T)
#pragma unroll
  for (int j = 0; j < 16; ++j) mv[j] = 3000.f;

  const int rsw = (cq & 7) << 4;    // read-side XOR (same for rows cq, cq+32)

  auto stage = [&](int buf, int s0) {
#pragma unroll
    for (int c = 0; c < 4; ++c) {
      int row = 16 * c + 8 * w + (lane >> 3);
      int src = (((lane & 7) ^ (lane >> 3)) << 4);
      gl_lds16((const char*)Kb + ((size_t)(s0 + row) * DM + h * DK) * 2 + src,
               (char*)&Ks[buf][0] + w * 1024 + c * 2048);
      gl_lds16((const char*)Vt + ((size_t)(h * DK + row) * SEQ + s0) * 2 + src,
               (char*)&Vs[buf][0] + w * 1024 + c * 2048);
    }
  };

  stage(0, 0);
  const int NT = SEQ / 64;
  for (int t = 0; t < NT; ++t) {
    const int cur = t & 1;
    __syncthreads();                 // stage(t) landed; prior reads of other buf done
    if (t < NT - 1) stage(cur ^ 1, (t + 1) * 64);
    const char* kb = (const char*)&Ks[cur][0];
    const char* vb = (const char*)&Vs[cur][0];

    // S^T - m : kv-blocks 0 (rows cq) and 1 (rows 32+cq)
    f32x16 s0v, s1v;
    __builtin_amdgcn_s_setprio(1);
    {
      bf16x8 kf = *(const bf16x8*)(kb + cq * 128 + ((hh * 16) ^ rsw));
      s0v = __builtin_amdgcn_mfma_f32_32x32x16_bf16(kf, qf[0], mv, 0, 0, 0);
      bf16x8 kg = *(const bf16x8*)(kb + (32 + cq) * 128 + ((hh * 16) ^ rsw));
      s1v = __builtin_amdgcn_mfma_f32_32x32x16_bf16(kg, qf[0], mv, 0, 0, 0);
    }
#pragma unroll
    for (int ks = 1; ks < 4; ++ks) {
      bf16x8 kf = *(const bf16x8*)(kb + cq * 128 + ((ks * 32 + hh * 16) ^ rsw));
      s0v = __builtin_amdgcn_mfma_f32_32x32x16_bf16(kf, qf[ks], s0v, 0, 0, 0);
      bf16x8 kg = *(const bf16x8*)(kb + (32 + cq) * 128 + ((ks * 32 + hh * 16) ^ rsw));
      s1v = __builtin_amdgcn_mfma_f32_32x32x16_bf16(kg, qf[ks], s1v, 0, 0, 0);
    }
    __builtin_amdgcn_s_setprio(0);

    // column max over this tile's 64 kv (in-lane tree + cross-half shfl)
    float mx[16];
#pragma unroll
    for (int j = 0; j < 16; ++j) mx[j] = fmaxf(s0v[j], s1v[j]);
#pragma unroll
    for (int sstep = 8; sstep > 0; sstep >>= 1)
#pragma unroll
      for (int j = 0; j < sstep; ++j) mx[j] = fmaxf(mx[j], mx[j + sstep]);
    float lm = fmaxf(mx[0], __shfl_xor(mx[0], 32));

    if (!__all(lm <= 8.f)) {         // defer-max: rare after first tile
      float dm = fmaxf(lm, 0.f);
      float al = exp2f(-dm);
#pragma unroll
      for (int j = 0; j < 16; ++j) {
        s0v[j] -= dm; s1v[j] -= dm;
        o0[j] *= al;  o1[j] *= al;
        mv[j] -= dm;
      }
      ol *= al;
    }

    // P = exp2(S - m); denom sum; pack to bf16 pairs
    float p0[16], p1[16];
#pragma unroll
    for (int j = 0; j < 16; ++j) { p0[j] = exp2f(s0v[j]); p1[j] = exp2f(s1v[j]); }
    float sm[16];
#pragma unroll
    for (int j = 0; j < 16; ++j) sm[j] = p0[j] + p1[j];
#pragma unroll
    for (int sstep = 8; sstep > 0; sstep >>= 1)
#pragma unroll
      for (int j = 0; j < sstep; ++j) sm[j] += sm[j + sstep];
    ol += sm[0];

    uint32_t pk[16];                 // pk[q'*2 + lohi]; quad q' holds kv base 8q'+4hh
#pragma unroll
    for (int c = 0; c < 4; ++c) {
      pk[c * 2 + 0] = cvtpk(p0[4 * c + 0], p0[4 * c + 1]);
      pk[c * 2 + 1] = cvtpk(p0[4 * c + 2], p0[4 * c + 3]);
      pk[(4 + c) * 2 + 0] = cvtpk(p1[4 * c + 0], p1[4 * c + 1]);
      pk[(4 + c) * 2 + 1] = cvtpk(p1[4 * c + 2], p1[4 * c + 3]);
    }

    // O^T += Vt . P  (B-frag: own quads + cross-half quads via ds_bpermute)
    __builtin_amdgcn_s_setprio(1);
#pragma unroll
    for (int ks = 0; ks < 4; ++ks) {
      uint32_t a0 = pk[(2 * ks) * 2 + 0], a1 = pk[(2 * ks) * 2 + 1];
      uint32_t b0 = pk[(2 * ks + 1) * 2 + 0], b1 = pk[(2 * ks + 1) * 2 + 1];
      uint32_t ca0 = xlane(a0, lane), ca1 = xlane(a1, lane);
      uint32_t cb0 = xlane(b0, lane), cb1 = xlane(b1, lane);
      union { u32x4 u; bf16x8 b; } pf;
      pf.u[0] = hh ? cb0 : a0;       // hh=0: own 2ks (kv 16ks+0..3)  | hh=1: cross 2ks+1 (16ks+8..11)
      pf.u[1] = hh ? cb1 : a1;
      pf.u[2] = hh ? b0 : ca0;       // hh=0: cross 2ks (16ks+4..7)   | hh=1: own 2ks+1 (16ks+12..15)
      pf.u[3] = hh ? b1 : ca1;
      bf16x8 vf0 = *(const bf16x8*)(vb + cq * 128 + ((ks * 32 + hh * 16) ^ rsw));
      o0 = __builtin_amdgcn_mfma_f32_32x32x16_bf16(vf0, pf.b, o0, 0, 0, 0);
      bf16x8 vf1 = *(const bf16x8*)(vb + (32 + cq) * 128 + ((ks * 32 + hh * 16) ^ rsw));
      o1 = __builtin_amdgcn_mfma_f32_32x32x16_bf16(vf1, pf.b, o1, 0, 0, 0);
    }
    __builtin_amdgcn_s_setprio(0);
  }

  // epilogue: combine denom halves, normalize, pack 4 consecutive d per store
  float inv = 1.f / (ol + __shfl_xor(ol, 32));
  short* cp = ctx + (size_t)qrow * DM + h * DK;
#pragma unroll
  for (int rg = 0; rg < 4; ++rg) {
    int d0 = 8 * rg + 4 * hh;
    u32x2 w0, w1;
    w0[0] = cvtpk(o0[4 * rg + 0] * inv, o0[4 * rg + 1] * inv);
    w0[1] = cvtpk(o0[4 * rg + 2] * inv, o0[4 * rg + 3] * inv);
    *(u32x2*)(cp + d0) = w0;
    w1[0] = cvtpk(o1[4 * rg + 0] * inv, o1[4 * rg + 1] * inv);
    w1[1] = cvtpk(o1[4 * rg + 2] * inv, o1[4 * rg + 3] * inv);
    *(u32x2*)(cp + 32 + d0) = w1;
  }
}

extern "C" void kernel_launch(void* const* d_in, const int* in_sizes, int n_in,
                              void* d_out, int out_size, void* d_ws, size_t ws_size,
                              hipStream_t stream) {
  const float* x  = (const float*)d_in[0];
  const float* Wq = (const float*)d_in[1];
  const float* bq = (const float*)d_in[2];
  const float* Wk = (const float*)d_in[3];
  const float* bk = (const float*)d_in[4];
  const float* Wv = (const float*)d_in[5];
  const float* bv = (const float*)d_in[6];
  const float* Wo = (const float*)d_in[7];
  const float* bo = (const float*)d_in[8];

  char* ws = (char*)d_ws;
  short* xb  = (short*)(ws + (size_t)0);
  short* Wt  = (short*)(ws + ((size_t)8 << 20));
  short* Qb  = (short*)(ws + ((size_t)16 << 20));
  short* Kb  = (short*)(ws + ((size_t)24 << 20));
  short* Vb  = (short*)(ws + ((size_t)32 << 20));
  short* Vt  = (short*)(ws + ((size_t)40 << 20));
  short* ctx = (short*)(ws + ((size_t)48 << 20));

  cvt_x_k<<<2048, 256, 0, stream>>>(x, xb);
  cvt_wt_k<<<dim3(16, 16, 4), 256, 0, stream>>>(Wq, Wk, Wv, Wo, Wt);
  gemm_qkv<<<dim3(DM / 128, SEQ / 128, 3), 256, 0, stream>>>(xb, Wt, bq, bk, bv, Qb);
  trans_v_k<<<dim3(SEQ / 64, NH), 256, 0, stream>>>(Vb, Vt);
  attn_k<<<dim3(SEQ / 64, NH), 128, 0, stream>>>(Qb, Kb, Vt, ctx);
  gemm_out<<<dim3(DM / 128, SEQ / 128), 256, 0, stream>>>(
      ctx, Wt + (size_t)3 * (DM * DM), bo, (float*)d_out);
}